// Round 5
// baseline (1443.783 us; speedup 1.0000x reference)
//
#include <hip/hip_runtime.h>
#include <hip/hip_bf16.h>

// Sizes (fixed by the problem)
#define TT 256
#define BB 128
#define EE 256
#define HH 512
#define KK 7
#define WLD 776  // padded LDS row: 768 + 8 bf16

typedef short bf16x8 __attribute__((ext_vector_type(8)));
typedef float f32x4 __attribute__((ext_vector_type(4)));
typedef unsigned short u16x8 __attribute__((ext_vector_type(8)));

__device__ __forceinline__ unsigned short f2bf(float x) {
  unsigned u = __builtin_bit_cast(unsigned, x);
  u += 0x7FFFu + ((u >> 16) & 1u);  // RNE
  return (unsigned short)(u >> 16);
}
__device__ __forceinline__ float bf2f(unsigned short b) {
  return __builtin_bit_cast(float, (unsigned)b << 16);
}

// L1-bypass 16B load (sc0): reads the XCD-local L2 directly so same-XCD
// producer stores are seen. No waitcnt inside; caller counts vmcnt.
__device__ __forceinline__ bf16x8 gload_sc0(const unsigned short* p) {
  bf16x8 v;
  asm volatile("global_load_dwordx4 %0, %1, off sc0" : "=v"(v) : "v"(p) : "memory");
  return v;
}
// plain cached 16B load (read-only data), asm so vmcnt counting stays exact
__device__ __forceinline__ bf16x8 gload16(const unsigned short* p) {
  bf16x8 v;
  asm volatile("global_load_dwordx4 %0, %1, off" : "=v"(v) : "v"(p) : "memory");
  return v;
}

// ---------------------------------------------------------------------------
// K1: embedding gather -> bf16, layout xsb[t][b][e]
// ---------------------------------------------------------------------------
__global__ __launch_bounds__(256) void embed_kernel(
    const int* __restrict__ ids, const float* __restrict__ emb,
    unsigned short* __restrict__ xsb) {
  const int t = blockIdx.x, tid = threadIdx.x;
  const int b = tid >> 1, half = tid & 1;
  const int id = ids[t * BB + b];
  const float4* src = (const float4*)(emb + (size_t)id * EE + half * 128);
  unsigned short* dst = xsb + ((size_t)t * BB + b) * EE + half * 128;
#pragma unroll
  for (int i = 0; i < 32; ++i) {
    const float4 v = src[i];
    ushort4 o;
    o.x = f2bf(v.x); o.y = f2bf(v.y); o.z = f2bf(v.z); o.w = f2bf(v.w);
    *(ushort4*)(dst + i * 4) = o;
  }
}

// ---------------------------------------------------------------------------
// K2: persistent BiLSTM, XCD-local. 256 wgs x 128 thr (1 wg/CU by LDS).
//  XCD group g: dir = g>>2, rows = (g&3)*32.  slot (claimed): cols [s*16,+16).
//  2 waves: kh0 = x(8 ktiles) + h(0..3);  kh1 = h(4..15).  96 MFMA each.
//  Barrier: per-wg arrival FLAG store + all-lane poll of the 32-flag line
//  (no atomic RMW contention).  x double-buffered in registers (prefetch t+1).
// ---------------------------------------------------------------------------
__global__ __launch_bounds__(128, 1) void bilstm_kernel(
    const unsigned short* __restrict__ xsb,
    const float* __restrict__ Wih_f, const float* __restrict__ Whh_f,
    const float* __restrict__ bih_f, const float* __restrict__ bhh_f,
    const float* __restrict__ Wih_b, const float* __restrict__ Whh_b,
    const float* __restrict__ bih_b, const float* __restrict__ bhh_b,
    unsigned short* __restrict__ hbuf, unsigned short* __restrict__ hs,
    int* __restrict__ bar) {
  __shared__ unsigned short Wl[64][WLD];  // 99328 B
  __shared__ f32x4 gt[2][2][4][64];       // 16384 B  [kh][m][gate][lane]
  __shared__ int sinfo[2];

  const int tid = threadIdx.x;
  if (tid == 0) {
    const unsigned xcd = __builtin_amdgcn_s_getreg(14356) & 7;  // HW_REG_XCC_ID
    sinfo[0] = (int)xcd;
    sinfo[1] = atomicAdd(&bar[512 + xcd], 1);  // claim slot within XCD
  }
  __syncthreads();
  const int g = sinfo[0];
  const int slot = sinfo[1] & 31;
  const int dir = g >> 2;
  const int r0 = (g & 3) * 32;  // batch-row base
  const int j0 = slot * 16;     // h-column base
  int* arr = bar + g * 64;      // 32 arrival flags (one 128B line per XCD)

  const float* Wih = dir ? Wih_b : Wih_f;
  const float* Whh = dir ? Whh_b : Whh_f;
  const float* bih = dir ? bih_b : bih_f;
  const float* bhh = dir ? bhh_b : bhh_f;

  // Stage weights f32->bf16 into LDS once. Row = gate*16 + jj, k = 0..767.
  for (int idx = tid; idx < 64 * 192; idx += 128) {
    const int r = idx / 192;
    const int k4 = (idx - r * 192) * 4;
    const int grow = (r >> 4) * HH + j0 + (r & 15);
    float4 v;
    if (k4 < EE) v = *(const float4*)(Wih + (size_t)grow * EE + k4);
    else v = *(const float4*)(Whh + (size_t)grow * HH + (k4 - EE));
    ushort4 o;
    o.x = f2bf(v.x); o.y = f2bf(v.y); o.z = f2bf(v.z); o.w = f2bf(v.w);
    *(ushort4*)&Wl[r][k4] = o;
  }
  const int lane = tid & 63, ln = lane & 15, kk = lane >> 4;
  const int kh = tid >> 6;  // wave id (k-split; also the m-tile it updates)

  const float bi_ = bih[0 * HH + j0 + ln] + bhh[0 * HH + j0 + ln];
  const float bf_ = bih[1 * HH + j0 + ln] + bhh[1 * HH + j0 + ln];
  const float bg_ = bih[2 * HH + j0 + ln] + bhh[2 * HH + j0 + ln];
  const float bo_ = bih[3 * HH + j0 + ln] + bhh[3 * HH + j0 + ln];

  const unsigned short* wlp0 = &Wl[0 * 16 + ln][kk * 8];
  const unsigned short* wlp1 = &Wl[1 * 16 + ln][kk * 8];
  const unsigned short* wlp2 = &Wl[2 * 16 + ln][kk * 8];
  const unsigned short* wlp3 = &Wl[3 * 16 + ln][kk * 8];

  float c[4] = {0.f, 0.f, 0.f, 0.f};

  // preamble x for first step (kh0 only), via cached C loads
  bf16x8 xc0[8], xc1[8];
  if (kh == 0) {
    const int t0 = dir ? TT - 1 : 0;
    const unsigned short* xr0 = xsb + ((size_t)t0 * BB + r0 + ln) * EE + kk * 8;
    const unsigned short* xr1 = xr0 + (size_t)16 * EE;
#pragma unroll
    for (int i = 0; i < 8; ++i) {
      xc0[i] = *(const bf16x8*)(xr0 + i * 32);
      xc1[i] = *(const bf16x8*)(xr1 + i * 32);
    }
  }
  __syncthreads();  // weights staged, x ready

#define MFMA8(AV0, AV1, OFF)                                               \
  {                                                                        \
    const bf16x8 b0 = *(const bf16x8*)(wlp0 + (OFF));                      \
    const bf16x8 b1 = *(const bf16x8*)(wlp1 + (OFF));                      \
    const bf16x8 b2 = *(const bf16x8*)(wlp2 + (OFF));                      \
    const bf16x8 b3 = *(const bf16x8*)(wlp3 + (OFF));                      \
    a00 = __builtin_amdgcn_mfma_f32_16x16x32_bf16(AV0, b0, a00, 0, 0, 0);  \
    a01 = __builtin_amdgcn_mfma_f32_16x16x32_bf16(AV0, b1, a01, 0, 0, 0);  \
    a02 = __builtin_amdgcn_mfma_f32_16x16x32_bf16(AV0, b2, a02, 0, 0, 0);  \
    a03 = __builtin_amdgcn_mfma_f32_16x16x32_bf16(AV0, b3, a03, 0, 0, 0);  \
    a10 = __builtin_amdgcn_mfma_f32_16x16x32_bf16(AV1, b0, a10, 0, 0, 0);  \
    a11 = __builtin_amdgcn_mfma_f32_16x16x32_bf16(AV1, b1, a11, 0, 0, 0);  \
    a12 = __builtin_amdgcn_mfma_f32_16x16x32_bf16(AV1, b2, a12, 0, 0, 0);  \
    a13 = __builtin_amdgcn_mfma_f32_16x16x32_bf16(AV1, b3, a13, 0, 0, 0);  \
  }

  for (int s = 0; s < TT; ++s) {
    const int t = dir ? (TT - 1 - s) : s;
    const int p = s & 1;
    // ---- wait for previous step's h (all-lane poll of the 32-flag line) ----
    if (s > 0) {
      int fv;
      do {
        fv = __hip_atomic_load(&arr[lane & 31], __ATOMIC_RELAXED,
                               __HIP_MEMORY_SCOPE_AGENT);
      } while (!__all(fv >= s));
    }
    f32x4 a00 = {0.f, 0.f, 0.f, 0.f}, a01 = a00, a02 = a00, a03 = a00;
    f32x4 a10 = a00, a11 = a00, a12 = a00, a13 = a00;
    bf16x8 hv0[12], hv1[12], xn0[8], xn1[8];
    const unsigned short* hbase = hbuf + ((size_t)(p * 8 + g) * 32) * HH + kk * 8;
    const unsigned short* hp0 = hbase + (size_t)ln * HH;
    const unsigned short* hp1 = hbase + (size_t)(16 + ln) * HH;

    if (kh == 0) {
      // issue h loads first (waited), then x(t+1) prefetch (not waited)
      if (s > 0) {
#pragma unroll
        for (int i = 0; i < 4; ++i) {
          hv0[i] = gload_sc0(hp0 + i * 32);
          hv1[i] = gload_sc0(hp1 + i * 32);
        }
      }
      if (s < TT - 1) {
        const int t2 = dir ? t - 1 : t + 1;
        const unsigned short* xr0 = xsb + ((size_t)t2 * BB + r0 + ln) * EE + kk * 8;
        const unsigned short* xr1 = xr0 + (size_t)16 * EE;
#pragma unroll
        for (int i = 0; i < 8; ++i) {
          xn0[i] = gload16(xr0 + i * 32);
          xn1[i] = gload16(xr1 + i * 32);
        }
      }
      if (s > 0) {
        if (s < TT - 1) asm volatile("s_waitcnt vmcnt(16)" ::: "memory");
        else            asm volatile("s_waitcnt vmcnt(0)" ::: "memory");
        __builtin_amdgcn_sched_barrier(0);
      }
      // x-part MFMAs from ready registers
#pragma unroll
      for (int kt = 0; kt < 8; ++kt) MFMA8(xc0[kt], xc1[kt], kt * 32);
      // h-part (ktiles 0..3)
      if (s > 0) {
#pragma unroll
        for (int i = 0; i < 4; ++i) MFMA8(hv0[i], hv1[i], EE + i * 32);
      }
    } else {
      if (s > 0) {
#pragma unroll
        for (int i = 0; i < 12; ++i) {
          hv0[i] = gload_sc0(hp0 + (4 + i) * 32);
          hv1[i] = gload_sc0(hp1 + (4 + i) * 32);
        }
        asm volatile("s_waitcnt vmcnt(0)" ::: "memory");
        __builtin_amdgcn_sched_barrier(0);
#pragma unroll
        for (int i = 0; i < 12; ++i) MFMA8(hv0[i], hv1[i], EE + (4 + i) * 32);
      }
    }
    // ---- exchange partials (b128, conflict-free) ----
    gt[kh][0][0][lane] = a00; gt[kh][0][1][lane] = a01;
    gt[kh][0][2][lane] = a02; gt[kh][0][3][lane] = a03;
    gt[kh][1][0][lane] = a10; gt[kh][1][1][lane] = a11;
    gt[kh][1][2][lane] = a12; gt[kh][1][3][lane] = a13;
    __syncthreads();
    // ---- cell update: wave kh handles m-tile = kh ----
    const f32x4 gi4 = gt[0][kh][0][lane] + gt[1][kh][0][lane];
    const f32x4 gf4 = gt[0][kh][1][lane] + gt[1][kh][1][lane];
    const f32x4 gg4 = gt[0][kh][2][lane] + gt[1][kh][2][lane];
    const f32x4 go4 = gt[0][kh][3][lane] + gt[1][kh][3][lane];
    unsigned short hbs[4];
    unsigned short* hw =
        hbuf + (((size_t)((p ^ 1) * 8 + g) * 32) + kh * 16 + kk * 4) * HH + j0 + ln;
#pragma unroll
    for (int r = 0; r < 4; ++r) {
      const float gi = gi4[r] + bi_;
      const float gf = gf4[r] + bf_;
      const float gg = gg4[r] + bg_;
      const float go = go4[r] + bo_;
      const float si = 1.f / (1.f + __expf(-gi));
      const float sf = 1.f / (1.f + __expf(-gf));
      const float so = 1.f / (1.f + __expf(-go));
      const float gcl = fminf(fmaxf(gg, -30.f), 30.f);
      const float eg = __expf(-2.f * gcl);
      const float tg = (1.f - eg) / (1.f + eg);
      const float cn = fmaf(sf, c[r], si * tg);
      c[r] = cn;
      const float ccl = fminf(fmaxf(cn, -30.f), 30.f);
      const float ec = __expf(-2.f * ccl);
      const float tc = (1.f - ec) / (1.f + ec);
      const float hn = so * tc;
      hbs[r] = f2bf(hn);
      hw[(size_t)r * HH] = hbs[r];
    }
    __syncthreads();  // drains hbuf stores of BOTH waves, then release:
    if (tid == 0)
      __hip_atomic_store(&arr[slot], s + 1, __ATOMIC_RELAXED,
                         __HIP_MEMORY_SCOPE_AGENT);
    // ---- off critical path: hs store + x reg double-buffer swap ----
    unsigned short* hsw =
        hs + ((size_t)t * BB + r0 + kh * 16 + kk * 4) * 1024 + dir * HH + j0 + ln;
#pragma unroll
    for (int r = 0; r < 4; ++r) hsw[(size_t)r * 1024] = hbs[r];
    if (kh == 0 && s < TT - 1) {
#pragma unroll
      for (int i = 0; i < 8; ++i) { xc0[i] = xn0[i]; xc1[i] = xn1[i]; }
    }
  }
#undef MFMA8
}

// ---------------------------------------------------------------------------
// K3: emissions. Wave-per-b, lanes own 16-element j-slices of the 1024-dot.
// ---------------------------------------------------------------------------
__global__ __launch_bounds__(256) void emissions_kernel(
    const unsigned short* __restrict__ hs, const float* __restrict__ linW,
    const float* __restrict__ linb, float* __restrict__ em) {
  const int t = blockIdx.x, tid = threadIdx.x;
  const int wv = tid >> 6, l = tid & 63;
  for (int b = wv; b < BB; b += 4) {
    const unsigned short* hr = hs + ((size_t)t * BB + b) * 1024 + l * 16;
    const u16x8 v0 = *(const u16x8*)(hr);
    const u16x8 v1 = *(const u16x8*)(hr + 8);
    float x[16];
#pragma unroll
    for (int j = 0; j < 8; ++j) {
      x[j] = bf2f(v0[j]);
      x[8 + j] = bf2f(v1[j]);
    }
    float acc[KK];
#pragma unroll
    for (int k = 0; k < KK; ++k) {
      const float* wr = linW + (size_t)k * 1024 + l * 16;
      float ssum = 0.f;
#pragma unroll
      for (int j = 0; j < 16; ++j) ssum = fmaf(x[j], wr[j], ssum);
      acc[k] = ssum;
    }
#pragma unroll
    for (int k = 0; k < KK; ++k) {
#pragma unroll
      for (int off = 32; off > 0; off >>= 1) acc[k] += __shfl_xor(acc[k], off);
    }
    if (l == 0) {
      float* o = em + ((size_t)b * TT + t) * KK;
#pragma unroll
      for (int k = 0; k < KK; ++k) o[k] = acc[k] + linb[k];
    }
  }
}

// ---------------------------------------------------------------------------
// K4: CRF. One wave per sequence. 8 lane-groups of 8: dst=group, src=lane%8.
// Shuffle logsumexp + ds_bpermute alpha broadcast; gold score parallel in t.
// ---------------------------------------------------------------------------
__global__ __launch_bounds__(64) void crf_kernel(
    const float* __restrict__ em, const int* __restrict__ lab,
    const float* __restrict__ trans, const float* __restrict__ st_,
    const float* __restrict__ en_, float* __restrict__ partial) {
  const int b = blockIdx.x, lane = threadIdx.x;
  const float* e = em + (size_t)b * TT * KK;
  const int* lb = lab + (size_t)b * TT;
  // gold path score, parallel over t
  float gp = 0.f;
  for (int t = lane; t < TT; t += 64) {
    const int lt = lb[t];
    gp += e[t * KK + lt];
    if (t > 0) gp += trans[lb[t - 1] * KK + lt];
  }
#pragma unroll
  for (int o = 32; o; o >>= 1) gp += __shfl_xor(gp, o);
  // forward algorithm
  const int dst = lane >> 3, src = lane & 7;
  const bool vs = (src < 7), vd = (dst < 7);
  const float trv = (vs && vd) ? trans[src * KK + dst] : 0.f;
  float alb = vs ? (st_[src] + e[src]) : -1e30f;
  for (int t = 1; t < TT; ++t) {
    const float ev = vd ? e[t * KK + dst] : 0.f;
    float v = vs ? (alb + trv) : -1e30f;
    float mx = v;
#pragma unroll
    for (int o = 1; o < 8; o <<= 1) mx = fmaxf(mx, __shfl_xor(mx, o));
    float sm = __expf(v - mx);
#pragma unroll
    for (int o = 1; o < 8; o <<= 1) sm += __shfl_xor(sm, o);
    const float aln = mx + __logf(sm) + ev;  // new alpha[dst], valid group-wide
    // lane needs alpha[src]: pull from lane src*8 (group src, member 0)
    alb = __builtin_bit_cast(
        float, __builtin_amdgcn_ds_bpermute((lane & 7) * 32,
                                            __builtin_bit_cast(int, aln)));
    if (!vs) alb = -1e30f;
  }
  float v = (lane < 7) ? (alb + en_[lane]) : -1e30f;
  float mx = v;
#pragma unroll
  for (int o = 1; o < 8; o <<= 1) mx = fmaxf(mx, __shfl_xor(mx, o));
  float sm = __expf(v - mx);
#pragma unroll
  for (int o = 1; o < 8; o <<= 1) sm += __shfl_xor(sm, o);
  if (lane == 0) {
    const float logZ = mx + __logf(sm);
    const float gold = gp + st_[lb[0]] + en_[lb[TT - 1]];
    partial[b] = logZ - gold;
  }
}

// K5: final reduce
__global__ __launch_bounds__(128) void reduce_kernel(const float* __restrict__ partial,
                                                     float* __restrict__ out) {
  __shared__ float r[128];
  const int tid = threadIdx.x;
  r[tid] = partial[tid];
  __syncthreads();
  for (int off = 64; off > 0; off >>= 1) {
    if (tid < off) r[tid] += r[tid + off];
    __syncthreads();
  }
  if (tid == 0) out[0] = r[0];
}

// ---------------------------------------------------------------------------
extern "C" void kernel_launch(void* const* d_in, const int* in_sizes, int n_in,
                              void* d_out, int out_size, void* d_ws, size_t ws_size,
                              hipStream_t stream) {
  const int* ids = (const int*)d_in[0];
  const int* lab = (const int*)d_in[1];
  const float* emb = (const float*)d_in[2];
  const float* Wih_f = (const float*)d_in[3];
  const float* Whh_f = (const float*)d_in[4];
  const float* bih_f = (const float*)d_in[5];
  const float* bhh_f = (const float*)d_in[6];
  const float* Wih_b = (const float*)d_in[7];
  const float* Whh_b = (const float*)d_in[8];
  const float* bih_b = (const float*)d_in[9];
  const float* bhh_b = (const float*)d_in[10];
  const float* linW = (const float*)d_in[11];
  const float* linb = (const float*)d_in[12];
  const float* trans = (const float*)d_in[13];
  const float* st = (const float*)d_in[14];
  const float* en = (const float*)d_in[15];
  float* out = (float*)d_out;

  // workspace layout (~85 MB)
  char* ws = (char*)d_ws;
  int* bar = (int*)ws;                                   // 4 KB: flags + claims
  unsigned short* xsb = (unsigned short*)(ws + 4096);    // T*B*E bf16 = 16.8 MB
  unsigned short* hbuf = xsb + (size_t)TT * BB * EE;     // 2*8*32*512 bf16 = 0.5 MB
  unsigned short* hs = hbuf + (size_t)2 * 8 * 32 * HH;   // T*B*1024 bf16 = 67 MB
  float* em = (float*)(hs + (size_t)TT * BB * 1024);
  float* partial = em + (size_t)BB * TT * KK;

  hipMemsetAsync(bar, 0, 4096, stream);

  embed_kernel<<<dim3(TT), dim3(256), 0, stream>>>(ids, emb, xsb);

  void* args[] = {(void*)&xsb,   (void*)&Wih_f, (void*)&Whh_f, (void*)&bih_f,
                  (void*)&bhh_f, (void*)&Wih_b, (void*)&Whh_b, (void*)&bih_b,
                  (void*)&bhh_b, (void*)&hbuf,  (void*)&hs,    (void*)&bar};
  hipLaunchCooperativeKernel((void*)bilstm_kernel, dim3(256), dim3(128),
                             args, 0, stream);

  emissions_kernel<<<dim3(TT), dim3(256), 0, stream>>>(hs, linW, linb, em);
  crf_kernel<<<dim3(BB), dim3(64), 0, stream>>>(em, lab, trans, st, en, partial);
  reduce_kernel<<<dim3(1), dim3(128), 0, stream>>>(partial, out);
}